// Round 6
// baseline (83.660 us; speedup 1.0000x reference)
//
#include <hip/hip_runtime.h>
#include <hip/hip_bf16.h>
#include <math.h>

typedef __attribute__((ext_vector_type(8))) short bf16x8;
typedef __attribute__((ext_vector_type(4))) float f32x4;
typedef __attribute__((ext_vector_type(4))) unsigned int u32x4;
typedef __attribute__((ext_vector_type(2))) unsigned int u32x2;

#define NSC    8
#define SLEN   4096
#define FEAT   64
#define CHUNK_B 8192      // one 64-row chunk of sigT2, bytes

// ---- compile-time scale layout (derived from np.logspace(0, log10 64, 8)) ----
// L = int(64 * 64^(i/7)); FRONT pads chosen so LF = L+FRONT ≡ 0 mod 4 and
// front slack ≥ 34 + 32*cact - L; SEG = LF + 64; all mod-4 aligned.
#define W4 10176                              // elems per copy (Σ SEG)
#define WG_ELEMS 40960                        // 4 copies padded to 81920 B
constexpr int L_[NSC]     = {64, 115, 210, 380, 689, 1248, 2261, 4096};
constexpr int LF_[NSC]    = {132, 196, 292, 452, 772, 1316, 2340, 4164};
constexpr int OFF_[NSC]   = {0, 196, 456, 812, 1328, 2164, 3544, 5948};
constexpr int BASES_[NSC] = {132, 392, 748, 1264, 2100, 3480, 5884, 10112};
constexpr int CACT_[NSC]  = {3, 5, 8, 13, 23, 40, 72, 129};

struct WavP { float step[NSC]; float isq[NSC]; };

// ---------------- kernel 1: build dilated, reversed, 4-shift-copy wavelet table
// copyq[x] = Rv(x+q), q=0..3; Rv(x) = w~[LF - x] for LF-L < x <= LF? precisely:
// k = LF - x in [0, L-1]; else 0.  w~(k) = interp(mother, k*step)*isq*sw.
__global__ void k_build_wav(const float* __restrict__ mw, const float* __restrict__ sw,
                            __hip_bfloat16* __restrict__ wg, WavP wp)
{
  int e = blockIdx.x * 256 + threadIdx.x;
  if (e >= WG_ELEMS) return;
  float val = 0.f;
  if (e < 4 * W4) {
    int q = e / W4;
    int x = e - q * W4;
    int s = 0;
    #pragma unroll
    for (int i = 1; i < NSC; ++i) if (x >= OFF_[i]) s = i;
    int xl = x - OFF_[s] + q;
    int k = LF_[s] - xl;
    if (k >= 0 && k < L_[s]) {
      float pos = (float)k * wp.step[s];
      int ii = (int)pos;
      float r;
      if (ii >= 63) r = mw[s * 64 + 63];
      else {
        float a = mw[s * 64 + ii];
        r = fmaf(pos - (float)ii, mw[s * 64 + ii + 1] - a, a);
      }
      val = r * wp.isq[s] * sw[s];
    }
  }
  wg[e] = __float2bfloat16(val);
}

// ---------------- kernel 2: signal f32 [b][r][f] -> bf16 FRAGMENT-ORDERED -------
// Per 64-row chunk (b*64+rb): element e = h*2048 + n*512 + l*8 + i holds
// sig[r = rb*64 + h*32 + (l>>4)*8 + i][f = n*16 + (l&15)].
__global__ __launch_bounds__(256) void k_transpose(const float* __restrict__ sig,
                                                   __hip_bfloat16* __restrict__ sigT2)
{
  __shared__ float t[4096];                 // flat [r][f], XOR-swizzled banks
  const int tid = threadIdx.x;
  const float* sp = sig + (size_t)blockIdx.x * 4096;
  for (int idx = tid; idx < 4096; idx += 256) {
    int r = idx >> 6, f = idx & 63;
    t[(r << 6) + (f ^ ((r & 7) << 3))] = sp[idx];
  }
  __syncthreads();
  __hip_bfloat16* op = sigT2 + (size_t)blockIdx.x * 4096;
  for (int e = tid; e < 4096; e += 256) {
    int h = e >> 11, n = (e >> 9) & 3, l = (e >> 3) & 63, i = e & 7;
    int f = n * 16 + (l & 15);
    int r = h * 32 + (l >> 4) * 8 + i;
    op[e] = __float2bfloat16(t[(r << 6) + (f ^ ((r & 7) << 3))]);
  }
}

// ---------------- kernel 3: banded-Toeplitz MFMA convolution --------------------
// Block = 256 thr = 4 waves; block owns (b, 64-t tile); wave tw owns rows t0+16tw..+15.
// LDS: 4-shift-copy wavelet table (80 KiB, 2 blocks/CU). A-reads: two aligned
// ds_read_b64 per (s,step) with compile-time byte-immediate 2*BASES_[s], shared
// vaddr decremented 64B/step. B streams from global, chunk-deep double-buffered.
__global__ __launch_bounds__(256, 2) void k_wavelet_mfma(
    const __hip_bfloat16* __restrict__ sigT2,
    const __hip_bfloat16* __restrict__ wavg,
    float* __restrict__ out)
{
  __shared__ __align__(16) short ldsW[WG_ELEMS];   // 81920 B

  const int tid = threadIdx.x;
  const int bid = blockIdx.x;
  const int tt  = 63 - (bid >> 4);        // heavy (large t0) tiles first
  const int b   = bid & 15;
  const int t0  = tt * 64;
  const int tw  = tid >> 6;               // wave id
  const int fl  = tid & 15;               // lane&15: A-row / B-col / D-col
  const int g   = (tid >> 4) & 3;         // lane>>4: k-group / D-row-group

  // stage wavelet table (81920 B) into LDS once, 16B per lane per issue
  {
    const char* gp = (const char*)wavg;
    char* lp = (char*)ldsW;
    #pragma unroll
    for (int it = 0; it < 20; ++it)
      __builtin_amdgcn_global_load_lds(
        (const __attribute__((address_space(1))) void*)(gp + it * 4096 + tid * 16),
        (__attribute__((address_space(3))) void*)(lp + it * 4096 + (tid >> 6) * 1024),
        16, 0, 0);
  }
  __syncthreads();                        // only barrier in the kernel

  // lane-constant A addressing: copy q4 = (-fl)&3 makes element index ≡ 0 mod 4
  const int q4    = (16 - fl) & 3;
  const int laneA = q4 * W4 + (32 - 16 * tw + 8 * g - fl - q4);

  const int C = tt + 1;                   // chunks: rows [64(tt-c), +63], c=0..C-1
  const char* cb = (const char*)sigT2 + ((size_t)(b * 64 + tt)) * CHUNK_B
                   + (size_t)(tid & 63) * 16;

  f32x4 acc[NSC][4];
  const f32x4 z = {0.f, 0.f, 0.f, 0.f};
  #pragma unroll
  for (int s = 0; s < NSC; ++s)
    #pragma unroll
    for (int n = 0; n < 4; ++n) acc[s][n] = z;

  bf16x8 Ba[8], Bb[8];
  // prefetch may dangle up to 2 chunks below rb=0 -> still inside d_ws (sigT2 at +128KB)
  auto loadchunk = [&](int c, bf16x8* B) {
    const char* p = cb - (size_t)c * CHUNK_B;
    #pragma unroll
    for (int hn = 0; hn < 8; ++hn)
      B[hn] = *(const bf16x8*)(p + (hn >> 2) * 4096 + (hn & 3) * 1024);
  };

  auto compute = [&](int c_old, const bf16x8* Bf) {
    const int abase = laneA - 32 * c_old;
    __builtin_amdgcn_s_setprio(1);
    #pragma unroll
    for (int s = NSC - 1; s >= 0; --s) {
      if (c_old <= CACT_[s]) {            // wave-uniform; static indices
        const u32x2* pp = (const u32x2*)(ldsW + abase + BASES_[s]);  // 8B aligned
        u32x2 w0 = pp[0], w1 = pp[1];
        u32x4 au; au.x = w0.x; au.y = w0.y; au.z = w1.x; au.w = w1.y;
        bf16x8 Af = __builtin_bit_cast(bf16x8, au);
        acc[s][0] = __builtin_amdgcn_mfma_f32_16x16x32_bf16(Af, Bf[0], acc[s][0], 0, 0, 0);
        acc[s][1] = __builtin_amdgcn_mfma_f32_16x16x32_bf16(Af, Bf[1], acc[s][1], 0, 0, 0);
        acc[s][2] = __builtin_amdgcn_mfma_f32_16x16x32_bf16(Af, Bf[2], acc[s][2], 0, 0, 0);
        acc[s][3] = __builtin_amdgcn_mfma_f32_16x16x32_bf16(Af, Bf[3], acc[s][3], 0, 0, 0);
      }
    }
    __builtin_amdgcn_s_setprio(0);
  };

  loadchunk(0, Ba);

  for (int c = 0; c < C; c += 2) {
    loadchunk(c + 1, Bb);                 // in flight across Ba's compute
    compute(2 * c,     &Ba[4]);           // chunk c, h=1 (upper 32 rows)
    compute(2 * c + 1, &Ba[0]);           // chunk c, h=0
    loadchunk(c + 2, Ba);                 // in flight across Bb's compute
    if (c + 1 < C) {
      compute(2 * c + 2, &Bb[4]);
      compute(2 * c + 3, &Bb[0]);
    }
  }

  // epilogue: D row = 4*g + reg, col = 16n + fl
  const int trow = t0 + tw * 16 + g * 4;
  float* ob = out + (size_t)b * NSC * SLEN * FEAT;
  #pragma unroll
  for (int s = 0; s < NSC; ++s) {
    float* os = ob + (size_t)s * SLEN * FEAT;
    #pragma unroll
    for (int n = 0; n < 4; ++n)
      #pragma unroll
      for (int r = 0; r < 4; ++r)
        os[(size_t)(trow + r) * FEAT + n * 16 + fl] = acc[s][n][r];
  }
}

extern "C" void kernel_launch(void* const* d_in, const int* in_sizes, int n_in,
                              void* d_out, int out_size, void* d_ws, size_t ws_size,
                              hipStream_t stream) {
  const float* sig = (const float*)d_in[0];
  const float* mw  = (const float*)d_in[1];
  const float* sw  = (const float*)d_in[2];
  float*       out = (float*)d_out;

  // workspace layout: [0, 81920) wavelet table bf16; [131072, +8388608) sigT2 bf16
  __hip_bfloat16* wavg  = (__hip_bfloat16*)d_ws;
  __hip_bfloat16* sigT2 = (__hip_bfloat16*)((char*)d_ws + 131072);

  // runtime per-scale floats (same double math as np.logspace path)
  WavP wp;
  const double lg = log10(64.0), st = lg / 7.0;
  for (int i = 0; i < NSC; ++i) {
    double y = (i == 7) ? lg : (double)i * st;
    double s = pow(10.0, y);
    int L = L_[i];
    wp.step[i] = (float)(63.0 / (double)(L - 1));
    wp.isq[i]  = (float)(1.0 / sqrt(s));
  }

  k_build_wav<<<WG_ELEMS / 256, 256, 0, stream>>>(mw, sw, wavg, wp);
  k_transpose<<<1024, 256, 0, stream>>>(sig, sigT2);
  k_wavelet_mfma<<<1024, 256, 0, stream>>>(sigT2, wavg, out);
}